// Round 1
// baseline (2226.885 us; speedup 1.0000x reference)
//
#include <hip/hip_runtime.h>
#include <math.h>

#define BB 32
#define DD 2048
#define NH 16
#define NKVH 4
#define HDIM 128
#define MAXS 4096
#define FFD 8192
#define POS 4095
#define EPSV 1e-5f
#define SCALE 0.08838834764831845f
#define SPLITS 4
#define TSPLIT 1024

// workspace offsets (floats)
#define OFF_XA   0u
#define OFF_QKV  65536u      // 32 x 3072: q | k | v
#define OFF_RK   163840u     // 32 x 4 x 128 roped k (pos 4095)
#define OFF_RV   180224u     // 32 x 4 x 128 roped v
#define OFF_PART 196608u     // 32*4*4 splits*4 heads*130
#define OFF_Y    462848u     // 32 x 2048 attention out
#define OFF_H    528384u     // 32 x 2048 residual
#define OFF_XF   593920u     // 32 x 2048 ffn rmsnorm
#define OFF_G1   659456u     // 32 x 8192
#define OFF_G2   921600u     // 32 x 8192

__global__ void zero_kernel(float* __restrict__ p, int n) {
    int i = blockIdx.x * 256 + threadIdx.x;
    if (i < n) p[i] = 0.f;
}

// rmsnorm over rows of length 2048; optionally copy input row to cpy (residual init)
__global__ void rmsnorm_kernel(const float* __restrict__ in, const float* __restrict__ g,
                               float* __restrict__ out, float* __restrict__ cpy) {
    int b = blockIdx.x;
    int tid = threadIdx.x; // 256
    const float* row = in + b * DD;
    float v[8];
    float ss = 0.f;
#pragma unroll
    for (int i = 0; i < 8; ++i) { v[i] = row[tid + i * 256]; ss += v[i] * v[i]; }
#pragma unroll
    for (int off = 32; off; off >>= 1) ss += __shfl_xor(ss, off);
    __shared__ float red[4];
    if ((tid & 63) == 0) red[tid >> 6] = ss;
    __syncthreads();
    ss = red[0] + red[1] + red[2] + red[3];
    float scale = rsqrtf(ss * (1.f / DD) + EPSV);
#pragma unroll
    for (int i = 0; i < 8; ++i) {
        int idx = tid + i * 256;
        out[b * DD + idx] = v[i] * g[idx] * scale;
        if (cpy) cpy[b * DD + idx] = v[i];
    }
}

// fused QKV gemv: cols 0..2047 -> wq, 2048..2559 -> wk, 2560..3071 -> wv
// grid (12, 8), dchunk 256, atomic accumulate into qkv (zero-initialized)
__global__ void gemv_qkv_kernel(const float* __restrict__ xa,
                                const float* __restrict__ wq, const float* __restrict__ wk,
                                const float* __restrict__ wv, float* __restrict__ qkv) {
    int n = blockIdx.x * 256 + threadIdx.x; // 0..3071 (uniform matrix per block)
    int d0 = blockIdx.y * 256;
    const float* W; int N; int col;
    if (n < 2048)      { W = wq; N = 2048; col = n; }
    else if (n < 2560) { W = wk; N = 512;  col = n - 2048; }
    else               { W = wv; N = 512;  col = n - 2560; }
    const float* Wp = W + (size_t)d0 * N + col;
    float acc[BB];
#pragma unroll
    for (int b = 0; b < BB; ++b) acc[b] = 0.f;
    for (int d = 0; d < 256; ++d) {
        float w = Wp[(size_t)d * N];
#pragma unroll
        for (int b = 0; b < BB; ++b) acc[b] += xa[b * DD + d0 + d] * w;
    }
#pragma unroll
    for (int b = 0; b < BB; ++b) atomicAdd(&qkv[b * 3072 + n], acc[b]);
}

// generic split-K gemv with atomic accumulate: C[b][n] += sum A[b][d]*W[d][n]
__global__ void gemv_atomic_kernel(const float* __restrict__ A, int K,
                                   const float* __restrict__ W, int N,
                                   float* __restrict__ C, int dChunk) {
    int n = blockIdx.x * 256 + threadIdx.x;
    int d0 = blockIdx.y * dChunk;
    const float* Wp = W + (size_t)d0 * N + n;
    float acc[BB];
#pragma unroll
    for (int b = 0; b < BB; ++b) acc[b] = 0.f;
    for (int d = 0; d < dChunk; ++d) {
        float w = Wp[(size_t)d * N];
#pragma unroll
        for (int b = 0; b < BB; ++b) acc[b] += A[b * K + d0 + d] * w;
    }
#pragma unroll
    for (int b = 0; b < BB; ++b) atomicAdd(&C[b * N + n], acc[b]);
}

// fused w1/w2 gemv: cols 0..8191 -> w1 -> g1, 8192..16383 -> w2 -> g2
// grid (64, 2), dchunk 1024
__global__ void gemv_w12_kernel(const float* __restrict__ xf, const float* __restrict__ w1,
                                const float* __restrict__ w2, float* __restrict__ g1,
                                float* __restrict__ g2) {
    int n = blockIdx.x * 256 + threadIdx.x; // 0..16383
    int d0 = blockIdx.y * 1024;
    const float* W; float* G; int col;
    if (n < FFD) { W = w1; G = g1; col = n; }
    else         { W = w2; G = g2; col = n - FFD; }
    const float* Wp = W + (size_t)d0 * FFD + col;
    float acc[BB];
#pragma unroll
    for (int b = 0; b < BB; ++b) acc[b] = 0.f;
    for (int d = 0; d < 1024; ++d) {
        float w = Wp[(size_t)d * FFD];
#pragma unroll
        for (int b = 0; b < BB; ++b) acc[b] += xf[b * DD + d0 + d] * w;
    }
#pragma unroll
    for (int b = 0; b < BB; ++b) atomicAdd(&G[b * FFD + col], acc[b]);
}

// rope on new k and v (reference ropes BOTH k and v; q is NOT roped)
__global__ void rope_kernel(const float* __restrict__ qkv, const float* __restrict__ cosb,
                            const float* __restrict__ sinb, float* __restrict__ rk,
                            float* __restrict__ rv) {
    int idx = blockIdx.x * 256 + threadIdx.x; // 32*4*64 = 8192 pairs
    int b = idx >> 8, rem = idx & 255;
    int kvh = rem >> 6, i = rem & 63;
    float c = cosb[i], s = sinb[i];
    const float* kp = qkv + b * 3072 + 2048 + kvh * HDIM + 2 * i;
    const float* vp = qkv + b * 3072 + 2560 + kvh * HDIM + 2 * i;
    float k0 = kp[0], k1 = kp[1], v0 = vp[0], v1 = vp[1];
    int o = (b * NKVH + kvh) * HDIM + 2 * i;
    rk[o] = k0 * c - k1 * s; rk[o + 1] = k0 * s + k1 * c;
    rv[o] = v0 * c - v1 * s; rv[o + 1] = v0 * s + v1 * c;
}

// attention partial: grid 512 = (b, kvh, split); 4 GQA heads share K/V reads.
// position POS (4095) comes from rk/rv, NOT the cache (inputs stay unmutated).
__global__ __launch_bounds__(256) void attn_partial_kernel(
    const float* __restrict__ qkv, const float* __restrict__ kc, const float* __restrict__ vc,
    const float* __restrict__ rk, const float* __restrict__ rv, float* __restrict__ part) {
    int bid = blockIdx.x;
    int b = bid >> 4, kvh = (bid >> 2) & 3, split = bid & 3;
    int tid = threadIdx.x;
    __shared__ float q_s[4][HDIM];
    __shared__ float p_s[4][TSPLIT];
    __shared__ float red_m[4], red_l[4];
    for (int i = tid; i < 4 * HDIM; i += 256)
        q_s[i >> 7][i & 127] = qkv[b * 3072 + (kvh * 4 + (i >> 7)) * HDIM + (i & 127)];
    __syncthreads();
    int t0 = split * TSPLIT;
    for (int it = 0; it < 4; ++it) {
        int tl = it * 256 + tid, t = t0 + tl;
        const float* krow = (t == POS) ? rk + (b * NKVH + kvh) * HDIM
                                       : kc + ((size_t)(b * MAXS + t) * NKVH + kvh) * HDIM;
        float s0 = 0, s1 = 0, s2 = 0, s3 = 0;
#pragma unroll
        for (int j = 0; j < HDIM; j += 4) {
            float4 kk = *(const float4*)(krow + j);
            s0 += kk.x * q_s[0][j] + kk.y * q_s[0][j + 1] + kk.z * q_s[0][j + 2] + kk.w * q_s[0][j + 3];
            s1 += kk.x * q_s[1][j] + kk.y * q_s[1][j + 1] + kk.z * q_s[1][j + 2] + kk.w * q_s[1][j + 3];
            s2 += kk.x * q_s[2][j] + kk.y * q_s[2][j + 1] + kk.z * q_s[2][j + 2] + kk.w * q_s[2][j + 3];
            s3 += kk.x * q_s[3][j] + kk.y * q_s[3][j + 1] + kk.z * q_s[3][j + 2] + kk.w * q_s[3][j + 3];
        }
        p_s[0][tl] = s0 * SCALE; p_s[1][tl] = s1 * SCALE;
        p_s[2][tl] = s2 * SCALE; p_s[3][tl] = s3 * SCALE;
    }
    __syncthreads();
    // per-head partial softmax: wave w handles head w
    {
        int w = tid >> 6, lane = tid & 63;
        float m = -INFINITY;
        for (int i = lane; i < TSPLIT; i += 64) m = fmaxf(m, p_s[w][i]);
#pragma unroll
        for (int off = 32; off; off >>= 1) m = fmaxf(m, __shfl_xor(m, off));
        float l = 0.f;
        for (int i = lane; i < TSPLIT; i += 64) {
            float e = __expf(p_s[w][i] - m);
            p_s[w][i] = e; l += e;
        }
#pragma unroll
        for (int off = 32; off; off >>= 1) l += __shfl_xor(l, off);
        if (lane == 0) { red_m[w] = m; red_l[w] = l; }
    }
    __syncthreads();
    if (tid < 8) {
        int r = tid >> 1;
        float* pb = part + ((((size_t)b * NKVH + kvh) * SPLITS + split) * 4 + r) * 130;
        if (tid & 1) pb[1] = red_l[r]; else pb[0] = red_m[r];
    }
    // V accumulation: thread = (rp, d); heads rp and rp+2
    int d = tid & 127, rp = tid >> 7;
    float a0 = 0.f, a1 = 0.f;
    int nloc = TSPLIT - ((split == 3) ? 1 : 0);
    const float* vbase = vc + ((size_t)(b * MAXS + t0) * NKVH + kvh) * HDIM + d;
#pragma unroll 4
    for (int tl = 0; tl < nloc; ++tl) {
        float vv = vbase[(size_t)tl * NKVH * HDIM];
        a0 += p_s[rp][tl] * vv;
        a1 += p_s[rp + 2][tl] * vv;
    }
    if (split == 3) {
        float vv = rv[(b * NKVH + kvh) * HDIM + d];
        a0 += p_s[rp][TSPLIT - 1] * vv;
        a1 += p_s[rp + 2][TSPLIT - 1] * vv;
    }
    float* pb0 = part + ((((size_t)b * NKVH + kvh) * SPLITS + split) * 4 + rp) * 130;
    float* pb1 = part + ((((size_t)b * NKVH + kvh) * SPLITS + split) * 4 + rp + 2) * 130;
    pb0[2 + d] = a0;
    pb1[2 + d] = a1;
}

// combine split partials: grid 512 = (b, h), 128 threads
__global__ void attn_combine_kernel(const float* __restrict__ part, float* __restrict__ y) {
    int bid = blockIdx.x;
    int b = bid >> 4, h = bid & 15;
    int kvh = h >> 2, r = h & 3;
    int d = threadIdx.x;
    const float* pb[SPLITS];
    float m[SPLITS], l[SPLITS];
    float M = -INFINITY;
#pragma unroll
    for (int s = 0; s < SPLITS; ++s) {
        pb[s] = part + ((((size_t)b * NKVH + kvh) * SPLITS + s) * 4 + r) * 130;
        m[s] = pb[s][0]; l[s] = pb[s][1];
        M = fmaxf(M, m[s]);
    }
    float denom = 0.f, acc = 0.f;
#pragma unroll
    for (int s = 0; s < SPLITS; ++s) {
        float e = __expf(m[s] - M);
        denom += l[s] * e;
        acc += e * pb[s][2 + d];
    }
    y[b * DD + h * HDIM + d] = acc / denom;
}

__global__ void silu_mul_kernel(float* __restrict__ g1, const float* __restrict__ g2) {
    int i = blockIdx.x * 256 + threadIdx.x; // 262144
    float a = g1[i], bb = g2[i];
    g1[i] = a * bb / (1.f + __expf(-a));
}

extern "C" void kernel_launch(void* const* d_in, const int* in_sizes, int n_in,
                              void* d_out, int out_size, void* d_ws, size_t ws_size,
                              hipStream_t stream) {
    (void)in_sizes; (void)n_in; (void)out_size; (void)ws_size;
    const float* x    = (const float*)d_in[0];
    const float* cosb = (const float*)d_in[1];
    const float* sinb = (const float*)d_in[2];
    const float* kc   = (const float*)d_in[3];
    const float* vc   = (const float*)d_in[4];
    const float* wra  = (const float*)d_in[5];
    const float* wq   = (const float*)d_in[6];
    const float* wk   = (const float*)d_in[7];
    const float* wv   = (const float*)d_in[8];
    const float* wo   = (const float*)d_in[9];
    const float* wrf  = (const float*)d_in[10];
    const float* w1   = (const float*)d_in[11];
    const float* w2   = (const float*)d_in[12];
    const float* w3   = (const float*)d_in[13];
    float* out = (float*)d_out;
    float* ws  = (float*)d_ws;

    float* xa   = ws + OFF_XA;
    float* qkv  = ws + OFF_QKV;
    float* rk   = ws + OFF_RK;
    float* rv   = ws + OFF_RV;
    float* part = ws + OFF_PART;
    float* y    = ws + OFF_Y;
    float* h    = ws + OFF_H;
    float* xf   = ws + OFF_XF;
    float* g1   = ws + OFF_G1;
    float* g2   = ws + OFF_G2;

    // zero atomic-accumulated buffers (every call; graph-replay safe)
    zero_kernel<<<384, 256, 0, stream>>>(qkv, 32 * 3072);
    zero_kernel<<<2048, 256, 0, stream>>>(g1, 2 * 32 * FFD); // g1,g2 contiguous

    // xa = rmsnorm(x), h = x
    rmsnorm_kernel<<<32, 256, 0, stream>>>(x, wra, xa, h);
    // q,k,v
    gemv_qkv_kernel<<<dim3(12, 8), 256, 0, stream>>>(xa, wq, wk, wv, qkv);
    // rope new k,v (cache is NOT mutated)
    rope_kernel<<<32, 256, 0, stream>>>(qkv, cosb, sinb, rk, rv);
    // attention (split along positions) + combine
    attn_partial_kernel<<<512, 256, 0, stream>>>(qkv, kc, vc, rk, rv, part);
    attn_combine_kernel<<<512, 128, 0, stream>>>(part, y);
    // h = x + y @ wo
    gemv_atomic_kernel<<<dim3(8, 8), 256, 0, stream>>>(y, DD, wo, DD, h, 256);
    // xf = rmsnorm(h), out = h
    rmsnorm_kernel<<<32, 256, 0, stream>>>(h, wrf, xf, out);
    // g1 = xf@w1, g2 = xf@w2
    gemv_w12_kernel<<<dim3(64, 2), 256, 0, stream>>>(xf, w1, w2, g1, g2);
    // g1 = silu(g1)*g2
    silu_mul_kernel<<<1024, 256, 0, stream>>>(g1, g2);
    // out += g1 @ w3
    gemv_atomic_kernel<<<dim3(8, 16), 256, 0, stream>>>(g1, FFD, w3, DD, out, 512);
}

// Round 2
// 1308.819 us; speedup vs baseline: 1.7014x; 1.7014x over previous
//
#include <hip/hip_runtime.h>
#include <math.h>

#define BB 32
#define DD 2048
#define NKVH 4
#define HDIM 128
#define MAXS 4096
#define FFD 8192
#define POS 4095
#define EPSV 1e-5f
#define SCALE 0.08838834764831845f

// workspace offsets (floats)
#define OFF_QT   0u        // 2048 x 32 (transposed q)
#define OFF_KT   65536u    // 512 x 32
#define OFF_VT   81920u    // 512 x 32
#define OFF_G1   98304u    // 8192 x 32
#define OFF_G2   360448u   // 8192 x 32
#define ZERO_N   622592u   // contiguous atomic-target region [0, ZERO_N)
#define OFF_XAT  622592u   // 2048 x 32
#define OFF_RK   688128u   // 32 x 4 x 128
#define OFF_RV   704512u
#define OFF_PML  720896u   // 2048 x {m,l}
#define OFF_PACC 724992u   // 2048 x 128
#define OFF_YT   987136u   // 2048 x 32
#define OFF_H    1052672u  // 32 x 2048 (normal)
#define OFF_XFT  1118208u  // 2048 x 32

#define REP32(M) M(0) M(1) M(2) M(3) M(4) M(5) M(6) M(7) M(8) M(9) M(10) M(11) M(12) M(13) M(14) M(15) M(16) M(17) M(18) M(19) M(20) M(21) M(22) M(23) M(24) M(25) M(26) M(27) M(28) M(29) M(30) M(31)
#define REP32A(M,X) M(0,X) M(1,X) M(2,X) M(3,X) M(4,X) M(5,X) M(6,X) M(7,X) M(8,X) M(9,X) M(10,X) M(11,X) M(12,X) M(13,X) M(14,X) M(15,X) M(16,X) M(17,X) M(18,X) M(19,X) M(20,X) M(21,X) M(22,X) M(23,X) M(24,X) M(25,X) M(26,X) M(27,X) M(28,X) M(29,X) M(30,X) M(31,X)

#define DECLA(i) float a##i = 0.f;
#define FMA1(i,k) a##i = fmaf(ap[(k)*32 + (i)], w##k, a##i);
#define ATOMT(i) atomicAdd(ct + (i), a##i);
#define ATOMN(i) atomicAdd(C + (size_t)(i)*N + n, a##i);

// 32-batch GEMV: C[b][n] += sum_d At[d][b] * W[d][n].
// At transposed [K][32]; W row-major [K][N]. TOUT: write C transposed [N][32].
template<int N, int CH, bool TOUT>
__device__ __forceinline__ void gemv_body(const float* __restrict__ At,
                                          const float* __restrict__ W,
                                          float* __restrict__ C, int colblk) {
    int n = colblk * 256 + (int)threadIdx.x;
    int d0 = blockIdx.y * CH;
    const float* Wp = W + (size_t)d0 * N + n;
    const float* ap = At + (size_t)d0 * 32;
    REP32(DECLA)
#pragma unroll 2
    for (int dd = 0; dd < CH; dd += 4) {
        float w0 = Wp[0];
        float w1 = Wp[(size_t)N];
        float w2 = Wp[(size_t)N * 2];
        float w3 = Wp[(size_t)N * 3];
        REP32A(FMA1, 0)
        REP32A(FMA1, 1)
        REP32A(FMA1, 2)
        REP32A(FMA1, 3)
        Wp += (size_t)N * 4;
        ap += 128;
    }
    if constexpr (TOUT) {
        float* ct = C + (size_t)n * 32;
        REP32(ATOMT)
    } else {
        REP32(ATOMN)
    }
}

template<int N, int CH, bool TOUT>
__global__ __launch_bounds__(256) void gemv32_kernel(const float* __restrict__ At,
                                                     const float* __restrict__ W,
                                                     float* __restrict__ C) {
    gemv_body<N, CH, TOUT>(At, W, C, blockIdx.x);
}

// two matrices side by side (block-uniform select), both transposed out
template<int N, int CH, int HALF>
__global__ __launch_bounds__(256) void gemv32_dual_kernel(const float* __restrict__ At,
        const float* __restrict__ W0, const float* __restrict__ W1,
        float* __restrict__ C0, float* __restrict__ C1) {
    int bx = blockIdx.x;
    if (bx < HALF) gemv_body<N, CH, true>(At, W0, C0, bx);
    else           gemv_body<N, CH, true>(At, W1, C1, bx - HALF);
}

__global__ void zero_kernel(float* __restrict__ p) {
    p[blockIdx.x * 256 + threadIdx.x] = 0.f;
}

// rmsnorm row b: outT[d][b] = norm; cpy[b][d] = raw input (residual)
__global__ void rmsnorm_kernel(const float* __restrict__ in, const float* __restrict__ g,
                               float* __restrict__ outT, float* __restrict__ cpy) {
    int b = blockIdx.x;
    int tid = threadIdx.x; // 256
    const float* row = in + b * DD;
    float v[8];
    float ss = 0.f;
#pragma unroll
    for (int i = 0; i < 8; ++i) { v[i] = row[tid + i * 256]; ss += v[i] * v[i]; }
#pragma unroll
    for (int off = 32; off; off >>= 1) ss += __shfl_xor(ss, off);
    __shared__ float red[4];
    if ((tid & 63) == 0) red[tid >> 6] = ss;
    __syncthreads();
    ss = red[0] + red[1] + red[2] + red[3];
    float scale = rsqrtf(ss * (1.f / DD) + EPSV);
#pragma unroll
    for (int i = 0; i < 8; ++i) {
        int idx = tid + i * 256;
        outT[(size_t)idx * 32 + b] = v[i] * g[idx] * scale;
        if (cpy) cpy[b * DD + idx] = v[i];
    }
}

// rope on new k and v (reference ropes BOTH k and v; q is NOT roped)
__global__ void rope_kernel(const float* __restrict__ kT, const float* __restrict__ vT,
                            const float* __restrict__ cosb, const float* __restrict__ sinb,
                            float* __restrict__ rk, float* __restrict__ rv) {
    int idx = blockIdx.x * 256 + threadIdx.x; // 8192
    int b = idx >> 8, rem = idx & 255;
    int kvh = rem >> 6, i = rem & 63;
    float c = cosb[i], s = sinb[i];
    int col = kvh * HDIM + 2 * i;
    float k0 = kT[(size_t)col * 32 + b], k1 = kT[(size_t)(col + 1) * 32 + b];
    float v0 = vT[(size_t)col * 32 + b], v1 = vT[(size_t)(col + 1) * 32 + b];
    int o = (b * NKVH + kvh) * HDIM + 2 * i;
    rk[o] = k0 * c - k1 * s; rk[o + 1] = k0 * s + k1 * c;
    rv[o] = v0 * c - v1 * s; rv[o + 1] = v0 * s + v1 * c;
}

// attention partial: grid 512 = (b, kvh, split of 1024 positions)
__global__ __launch_bounds__(256) void attn_partial_kernel(
    const float* __restrict__ qT, const float* __restrict__ kc, const float* __restrict__ vc,
    const float* __restrict__ rk, const float* __restrict__ rv,
    float* __restrict__ pml, float* __restrict__ pacc) {
    int bid = blockIdx.x;
    int b = bid >> 4, kvh = (bid >> 2) & 3, split = bid & 3;
    int tid = threadIdx.x;
    __shared__ float q_s[4][HDIM];
    __shared__ float p_s[4][1024];
    __shared__ float red[8][4][HDIM];
    for (int i = tid; i < 4 * HDIM; i += 256)
        q_s[i >> 7][i & 127] = qT[(size_t)(kvh * 512 + i) * 32 + b];
    __syncthreads();
    int t0 = split * 1024;
#pragma unroll
    for (int it = 0; it < 4; ++it) {
        int tl = it * 256 + tid, t = t0 + tl;
        const float* krow = (t == POS) ? rk + (b * NKVH + kvh) * HDIM
                                       : kc + ((size_t)(b * MAXS + t) * NKVH + kvh) * HDIM;
        float s0 = 0, s1 = 0, s2 = 0, s3 = 0;
#pragma unroll
        for (int j = 0; j < HDIM; j += 4) {
            float4 kk = *(const float4*)(krow + j);
            s0 += kk.x * q_s[0][j] + kk.y * q_s[0][j + 1] + kk.z * q_s[0][j + 2] + kk.w * q_s[0][j + 3];
            s1 += kk.x * q_s[1][j] + kk.y * q_s[1][j + 1] + kk.z * q_s[1][j + 2] + kk.w * q_s[1][j + 3];
            s2 += kk.x * q_s[2][j] + kk.y * q_s[2][j + 1] + kk.z * q_s[2][j + 2] + kk.w * q_s[2][j + 3];
            s3 += kk.x * q_s[3][j] + kk.y * q_s[3][j + 1] + kk.z * q_s[3][j + 2] + kk.w * q_s[3][j + 3];
        }
        p_s[0][tl] = s0 * SCALE; p_s[1][tl] = s1 * SCALE;
        p_s[2][tl] = s2 * SCALE; p_s[3][tl] = s3 * SCALE;
    }
    __syncthreads();
    { // per-head partial softmax: wave w handles head w
        int w = tid >> 6, lane = tid & 63;
        float m = -INFINITY;
        for (int i = lane; i < 1024; i += 64) m = fmaxf(m, p_s[w][i]);
#pragma unroll
        for (int off = 32; off; off >>= 1) m = fmaxf(m, __shfl_xor(m, off));
        float l = 0.f;
        for (int i = lane; i < 1024; i += 64) {
            float e = __expf(p_s[w][i] - m);
            p_s[w][i] = e; l += e;
        }
#pragma unroll
        for (int off = 32; off; off >>= 1) l += __shfl_xor(l, off);
        if (lane == 0) {
            int idx = ((b * NKVH + kvh) * 4 + split) * 4 + w;
            pml[2 * idx] = m; pml[2 * idx + 1] = l;
        }
    }
    __syncthreads();
    // V accumulation: thread = (tsub 0..7, q4 0..31 -> float4 of d)
    int tsub = tid >> 5, q4 = tid & 31;
    int tb = t0 + tsub * 128;
    const float* vbase = vc + ((size_t)(b * MAXS + tb) * NKVH + kvh) * HDIM + q4 * 4;
    float4 a0 = {0, 0, 0, 0}, a1 = a0, a2 = a0, a3 = a0;
    int jmax = (split == 3 && tsub == 7) ? 127 : 128;
#pragma unroll 4
    for (int j = 0; j < jmax; ++j) {
        float4 vv = *(const float4*)(vbase + (size_t)j * (NKVH * HDIM));
        int tl = tsub * 128 + j;
        float p0 = p_s[0][tl], p1 = p_s[1][tl], p2 = p_s[2][tl], p3 = p_s[3][tl];
        a0.x = fmaf(p0, vv.x, a0.x); a0.y = fmaf(p0, vv.y, a0.y); a0.z = fmaf(p0, vv.z, a0.z); a0.w = fmaf(p0, vv.w, a0.w);
        a1.x = fmaf(p1, vv.x, a1.x); a1.y = fmaf(p1, vv.y, a1.y); a1.z = fmaf(p1, vv.z, a1.z); a1.w = fmaf(p1, vv.w, a1.w);
        a2.x = fmaf(p2, vv.x, a2.x); a2.y = fmaf(p2, vv.y, a2.y); a2.z = fmaf(p2, vv.z, a2.z); a2.w = fmaf(p2, vv.w, a2.w);
        a3.x = fmaf(p3, vv.x, a3.x); a3.y = fmaf(p3, vv.y, a3.y); a3.z = fmaf(p3, vv.z, a3.z); a3.w = fmaf(p3, vv.w, a3.w);
    }
    if (split == 3 && tsub == 7) { // position POS comes from rv (cache unmutated)
        float4 vv = *(const float4*)(rv + (b * NKVH + kvh) * HDIM + q4 * 4);
        float p0 = p_s[0][1023], p1 = p_s[1][1023], p2 = p_s[2][1023], p3 = p_s[3][1023];
        a0.x = fmaf(p0, vv.x, a0.x); a0.y = fmaf(p0, vv.y, a0.y); a0.z = fmaf(p0, vv.z, a0.z); a0.w = fmaf(p0, vv.w, a0.w);
        a1.x = fmaf(p1, vv.x, a1.x); a1.y = fmaf(p1, vv.y, a1.y); a1.z = fmaf(p1, vv.z, a1.z); a1.w = fmaf(p1, vv.w, a1.w);
        a2.x = fmaf(p2, vv.x, a2.x); a2.y = fmaf(p2, vv.y, a2.y); a2.z = fmaf(p2, vv.z, a2.z); a2.w = fmaf(p2, vv.w, a2.w);
        a3.x = fmaf(p3, vv.x, a3.x); a3.y = fmaf(p3, vv.y, a3.y); a3.z = fmaf(p3, vv.z, a3.z); a3.w = fmaf(p3, vv.w, a3.w);
    }
    *(float4*)&red[tsub][0][q4 * 4] = a0;
    *(float4*)&red[tsub][1][q4 * 4] = a1;
    *(float4*)&red[tsub][2][q4 * 4] = a2;
    *(float4*)&red[tsub][3][q4 * 4] = a3;
    __syncthreads();
    if (tid < 128) {
        int h = tid >> 5, qq = tid & 31;
        float4 s = {0, 0, 0, 0};
#pragma unroll
        for (int r = 0; r < 8; ++r) {
            float4 t4 = *(const float4*)&red[r][h][qq * 4];
            s.x += t4.x; s.y += t4.y; s.z += t4.z; s.w += t4.w;
        }
        int idx = ((b * NKVH + kvh) * 4 + split) * 4 + h;
        *(float4*)(pacc + (size_t)idx * HDIM + qq * 4) = s;
    }
}

// combine split partials: grid 512 = (b, h), 128 threads; writes yT
__global__ void attn_combine_kernel(const float* __restrict__ pml,
                                    const float* __restrict__ pacc, float* __restrict__ yT) {
    int bid = blockIdx.x;
    int b = bid >> 4, h = bid & 15;
    int kvh = h >> 2, hl = h & 3;
    int d = threadIdx.x;
    float m[4], l[4];
    float M = -INFINITY;
#pragma unroll
    for (int s = 0; s < 4; ++s) {
        int idx = ((b * NKVH + kvh) * 4 + s) * 4 + hl;
        m[s] = pml[2 * idx]; l[s] = pml[2 * idx + 1];
        M = fmaxf(M, m[s]);
    }
    float denom = 0.f, acc = 0.f;
#pragma unroll
    for (int s = 0; s < 4; ++s) {
        int idx = ((b * NKVH + kvh) * 4 + s) * 4 + hl;
        float e = __expf(m[s] - M);
        denom += l[s] * e;
        acc += e * pacc[(size_t)idx * HDIM + d];
    }
    yT[(size_t)(h * HDIM + d) * 32 + b] = acc / denom;
}

__global__ void silu_mul_kernel(float* __restrict__ g1, const float* __restrict__ g2) {
    int i = blockIdx.x * 256 + threadIdx.x; // 262144
    float a = g1[i], bb = g2[i];
    g1[i] = a * bb / (1.f + __expf(-a));
}

extern "C" void kernel_launch(void* const* d_in, const int* in_sizes, int n_in,
                              void* d_out, int out_size, void* d_ws, size_t ws_size,
                              hipStream_t stream) {
    (void)in_sizes; (void)n_in; (void)out_size; (void)ws_size;
    const float* x    = (const float*)d_in[0];
    const float* cosb = (const float*)d_in[1];
    const float* sinb = (const float*)d_in[2];
    const float* kc   = (const float*)d_in[3];
    const float* vc   = (const float*)d_in[4];
    const float* wra  = (const float*)d_in[5];
    const float* wq   = (const float*)d_in[6];
    const float* wk   = (const float*)d_in[7];
    const float* wv   = (const float*)d_in[8];
    const float* wo   = (const float*)d_in[9];
    const float* wrf  = (const float*)d_in[10];
    const float* w1   = (const float*)d_in[11];
    const float* w2   = (const float*)d_in[12];
    const float* w3   = (const float*)d_in[13];
    float* out = (float*)d_out;
    float* ws  = (float*)d_ws;

    float* qT   = ws + OFF_QT;
    float* kT   = ws + OFF_KT;
    float* vT   = ws + OFF_VT;
    float* g1T  = ws + OFF_G1;
    float* g2T  = ws + OFF_G2;
    float* xaT  = ws + OFF_XAT;
    float* rk   = ws + OFF_RK;
    float* rv   = ws + OFF_RV;
    float* pml  = ws + OFF_PML;
    float* pacc = ws + OFF_PACC;
    float* yT   = ws + OFF_YT;
    float* h    = ws + OFF_H;
    float* xfT  = ws + OFF_XFT;

    // zero all atomic-accumulated buffers (qT,kT,vT,g1T,g2T contiguous)
    zero_kernel<<<ZERO_N / 256, 256, 0, stream>>>(ws);

    // xaT = rmsnorm(x)^T, h = x
    rmsnorm_kernel<<<32, 256, 0, stream>>>(x, wra, xaT, h);
    // q,k,v (transposed outputs)
    gemv32_kernel<2048, 64, true><<<dim3(8, 32), 256, 0, stream>>>(xaT, wq, qT);
    gemv32_dual_kernel<512, 64, 2><<<dim3(4, 32), 256, 0, stream>>>(xaT, wk, wv, kT, vT);
    // rope new k,v (cache NOT mutated)
    rope_kernel<<<32, 256, 0, stream>>>(kT, vT, cosb, sinb, rk, rv);
    // attention
    attn_partial_kernel<<<512, 256, 0, stream>>>(qT, kc, vc, rk, rv, pml, pacc);
    attn_combine_kernel<<<512, 128, 0, stream>>>(pml, pacc, yT);
    // h = x + y @ wo
    gemv32_kernel<2048, 64, false><<<dim3(8, 32), 256, 0, stream>>>(yT, wo, h);
    // xfT = rmsnorm(h)^T, out = h
    rmsnorm_kernel<<<32, 256, 0, stream>>>(h, wrf, xfT, out);
    // g1 = xf@w1, g2 = xf@w2 (transposed outputs)
    gemv32_dual_kernel<8192, 128, 32><<<dim3(64, 16), 256, 0, stream>>>(xfT, w1, w2, g1T, g2T);
    // g1 = silu(g1)*g2 (elementwise, layout-agnostic)
    silu_mul_kernel<<<1024, 256, 0, stream>>>(g1T, g2T);
    // out += g1 @ w3
    gemv32_kernel<2048, 128, false><<<dim3(8, 64), 256, 0, stream>>>(g1T, w3, out);
}

// Round 3
// 296.694 us; speedup vs baseline: 7.5057x; 4.4114x over previous
//
#include <hip/hip_runtime.h>
#include <math.h>

#define BB 32
#define DD 2048
#define NKVH 4
#define HDIM 128
#define MAXS 4096
#define FFD 8192
#define POS 4095
#define EPSV 1e-5f
#define SCALE 0.08838834764831845f
#define ASPLIT 16

// workspace offsets (floats)
#define OFF_QT   0u        // 2048 x 32 (transposed q)
#define OFF_KT   65536u    // 512 x 32
#define OFF_VT   81920u    // 512 x 32
#define OFF_G1   98304u    // 8192 x 32
#define OFF_G2   360448u   // 8192 x 32
#define ZERO_N   622592u   // contiguous atomic-target region [0, ZERO_N)
#define OFF_XAT  622592u   // 2048 x 32
#define OFF_RK   688128u   // 32 x 4 x 128
#define OFF_RV   704512u
#define OFF_PML  720896u   // 8192 x {m,l}
#define OFF_PACC 737280u   // 8192 x 128
#define OFF_YT   1785856u  // 2048 x 32
#define OFF_H    1851392u  // 32 x 2048 (normal)
#define OFF_XFT  1916928u  // 2048 x 32

#define REP32(M) M(0) M(1) M(2) M(3) M(4) M(5) M(6) M(7) M(8) M(9) M(10) M(11) M(12) M(13) M(14) M(15) M(16) M(17) M(18) M(19) M(20) M(21) M(22) M(23) M(24) M(25) M(26) M(27) M(28) M(29) M(30) M(31)
#define REP32A(M,X) M(0,X) M(1,X) M(2,X) M(3,X) M(4,X) M(5,X) M(6,X) M(7,X) M(8,X) M(9,X) M(10,X) M(11,X) M(12,X) M(13,X) M(14,X) M(15,X) M(16,X) M(17,X) M(18,X) M(19,X) M(20,X) M(21,X) M(22,X) M(23,X) M(24,X) M(25,X) M(26,X) M(27,X) M(28,X) M(29,X) M(30,X) M(31,X)

#define DECLA(i) float a##i = 0.f;
#define FMA1(i,k) a##i = fmaf(ap[(k)*32 + (i)], w##k, a##i);
#define STORET(i) tl[i] = a##i;
#define ATOMN(i) atomicAdd(C + (size_t)(i)*N + n, a##i);

// 32-batch GEMV: C[b][n] += sum_d At[d][b] * W[d][n].
// At transposed [K][32]; W row-major [K][N].
// TOUT: C transposed [N][32], staged via LDS, coalesced atomics.
template<int N, int CH, bool TOUT>
__device__ __forceinline__ void gemv_body(const float* __restrict__ At,
                                          const float* __restrict__ W,
                                          float* __restrict__ C, int colblk,
                                          float* tile) {
    int tid = (int)threadIdx.x;
    int n = colblk * 256 + tid;
    int d0 = blockIdx.y * CH;
    const float* Wp = W + (size_t)d0 * N + n;
    const float* ap = At + (size_t)d0 * 32;
    REP32(DECLA)
#pragma unroll 4
    for (int dd = 0; dd < CH; dd += 4) {
        float w0 = Wp[0];
        float w1 = Wp[(size_t)N];
        float w2 = Wp[(size_t)N * 2];
        float w3 = Wp[(size_t)N * 3];
        REP32A(FMA1, 0)
        REP32A(FMA1, 1)
        REP32A(FMA1, 2)
        REP32A(FMA1, 3)
        Wp += (size_t)N * 4;
        ap += 128;
    }
    if constexpr (TOUT) {
        float* tl = tile + tid * 33;           // padded row: bank-conflict-free
        REP32(STORET)
        __syncthreads();
        float* cb = C + (size_t)colblk * 256 * 32;
#pragma unroll
        for (int i = 0; i < 32; ++i) {
            int f = i * 256 + tid;             // coalesced atomic sweep
            atomicAdd(cb + f, tile[(f >> 5) * 33 + (f & 31)]);
        }
    } else {
        REP32(ATOMN)                           // lanes contiguous per i: coalesced
    }
}

template<int N, int CH, bool TOUT>
__global__ __launch_bounds__(256) void gemv32_kernel(const float* __restrict__ At,
                                                     const float* __restrict__ W,
                                                     float* __restrict__ C) {
    if constexpr (TOUT) {
        __shared__ float tile[256 * 33];
        gemv_body<N, CH, true>(At, W, C, blockIdx.x, tile);
    } else {
        gemv_body<N, CH, false>(At, W, C, blockIdx.x, nullptr);
    }
}

// two matrices side by side (block-uniform select), both transposed out
template<int N, int CH, int HALF>
__global__ __launch_bounds__(256) void gemv32_dual_kernel(const float* __restrict__ At,
        const float* __restrict__ W0, const float* __restrict__ W1,
        float* __restrict__ C0, float* __restrict__ C1) {
    __shared__ float tile[256 * 33];
    int bx = blockIdx.x;
    if (bx < HALF) gemv_body<N, CH, true>(At, W0, C0, bx, tile);
    else           gemv_body<N, CH, true>(At, W1, C1, bx - HALF, tile);
}

__global__ void zero_kernel(float* __restrict__ p) {
    p[blockIdx.x * 256 + threadIdx.x] = 0.f;
}

// rmsnorm row b: outT[d][b] = norm; cpy[b][d] = raw input (residual)
__global__ void rmsnorm_kernel(const float* __restrict__ in, const float* __restrict__ g,
                               float* __restrict__ outT, float* __restrict__ cpy) {
    int b = blockIdx.x;
    int tid = threadIdx.x; // 256
    const float* row = in + b * DD;
    float v[8];
    float ss = 0.f;
#pragma unroll
    for (int i = 0; i < 8; ++i) { v[i] = row[tid + i * 256]; ss += v[i] * v[i]; }
#pragma unroll
    for (int off = 32; off; off >>= 1) ss += __shfl_xor(ss, off);
    __shared__ float red[4];
    if ((tid & 63) == 0) red[tid >> 6] = ss;
    __syncthreads();
    ss = red[0] + red[1] + red[2] + red[3];
    float scale = rsqrtf(ss * (1.f / DD) + EPSV);
#pragma unroll
    for (int i = 0; i < 8; ++i) {
        int idx = tid + i * 256;
        outT[(size_t)idx * 32 + b] = v[i] * g[idx] * scale;
        if (cpy) cpy[b * DD + idx] = v[i];
    }
}

// rope on new k and v (reference ropes BOTH k and v; q is NOT roped)
__global__ void rope_kernel(const float* __restrict__ kT, const float* __restrict__ vT,
                            const float* __restrict__ cosb, const float* __restrict__ sinb,
                            float* __restrict__ rk, float* __restrict__ rv) {
    int idx = blockIdx.x * 256 + threadIdx.x; // 8192
    int b = idx >> 8, rem = idx & 255;
    int kvh = rem >> 6, i = rem & 63;
    float c = cosb[i], s = sinb[i];
    int col = kvh * HDIM + 2 * i;
    float k0 = kT[(size_t)col * 32 + b], k1 = kT[(size_t)(col + 1) * 32 + b];
    float v0 = vT[(size_t)col * 32 + b], v1 = vT[(size_t)(col + 1) * 32 + b];
    int o = (b * NKVH + kvh) * HDIM + 2 * i;
    rk[o] = k0 * c - k1 * s; rk[o + 1] = k0 * s + k1 * c;
    rv[o] = v0 * c - v1 * s; rv[o + 1] = v0 * s + v1 * c;
}

// attention partial: grid 2048 = (b, kvh, 16 splits of 256 positions)
__global__ __launch_bounds__(256) void attn_partial_kernel(
    const float* __restrict__ qT, const float* __restrict__ kc, const float* __restrict__ vc,
    const float* __restrict__ rk, const float* __restrict__ rv,
    float* __restrict__ pml, float* __restrict__ pacc) {
    int bid = blockIdx.x;
    int split = bid & 15, kvh = (bid >> 4) & 3, b = bid >> 6;
    int tid = threadIdx.x;
    __shared__ float q_s[4][HDIM];       // 2 KB
    __shared__ float p_s[4][256];        // 4 KB
    __shared__ float red[8][4][HDIM];    // 16 KB
    for (int i = tid; i < 4 * HDIM; i += 256)
        q_s[i >> 7][i & 127] = qT[(size_t)(kvh * 512 + i) * 32 + b];
    __syncthreads();
    int t0 = split * 256;
    // QK phase: one position per thread
    {
        int t = t0 + tid;
        const float* krow = (t == POS) ? rk + (b * NKVH + kvh) * HDIM
                                       : kc + ((size_t)(b * MAXS + t) * NKVH + kvh) * HDIM;
        float s0 = 0, s1 = 0, s2 = 0, s3 = 0;
#pragma unroll 8
        for (int j = 0; j < HDIM; j += 4) {
            float4 kk = *(const float4*)(krow + j);
            s0 += kk.x * q_s[0][j] + kk.y * q_s[0][j + 1] + kk.z * q_s[0][j + 2] + kk.w * q_s[0][j + 3];
            s1 += kk.x * q_s[1][j] + kk.y * q_s[1][j + 1] + kk.z * q_s[1][j + 2] + kk.w * q_s[1][j + 3];
            s2 += kk.x * q_s[2][j] + kk.y * q_s[2][j + 1] + kk.z * q_s[2][j + 2] + kk.w * q_s[2][j + 3];
            s3 += kk.x * q_s[3][j] + kk.y * q_s[3][j + 1] + kk.z * q_s[3][j + 2] + kk.w * q_s[3][j + 3];
        }
        p_s[0][tid] = s0 * SCALE; p_s[1][tid] = s1 * SCALE;
        p_s[2][tid] = s2 * SCALE; p_s[3][tid] = s3 * SCALE;
    }
    __syncthreads();
    { // per-head partial softmax: wave w handles head w (256 elems, 4/lane)
        int w = tid >> 6, lane = tid & 63;
        float e0 = p_s[w][lane], e1 = p_s[w][lane + 64];
        float e2 = p_s[w][lane + 128], e3 = p_s[w][lane + 192];
        float m = fmaxf(fmaxf(e0, e1), fmaxf(e2, e3));
#pragma unroll
        for (int off = 32; off; off >>= 1) m = fmaxf(m, __shfl_xor(m, off));
        e0 = __expf(e0 - m); e1 = __expf(e1 - m);
        e2 = __expf(e2 - m); e3 = __expf(e3 - m);
        p_s[w][lane] = e0; p_s[w][lane + 64] = e1;
        p_s[w][lane + 128] = e2; p_s[w][lane + 192] = e3;
        float l = e0 + e1 + e2 + e3;
#pragma unroll
        for (int off = 32; off; off >>= 1) l += __shfl_xor(l, off);
        if (lane == 0) {
            int idx = ((b * NKVH + kvh) * ASPLIT + split) * 4 + w;
            pml[2 * idx] = m; pml[2 * idx + 1] = l;
        }
    }
    __syncthreads();
    // PV phase: thread = (tsub 0..7 over 32 positions, q4 0..31 -> float4 of d)
    {
        int tsub = tid >> 5, q4 = tid & 31;
        int tb = t0 + tsub * 32;
        const float* vbase = vc + ((size_t)(b * MAXS + tb) * NKVH + kvh) * HDIM + q4 * 4;
        float4 a0 = {0, 0, 0, 0}, a1 = a0, a2 = a0, a3 = a0;
        int jmax = (split == ASPLIT - 1 && tsub == 7) ? 31 : 32;
#pragma unroll 4
        for (int j = 0; j < jmax; ++j) {
            float4 vv = *(const float4*)(vbase + (size_t)j * (NKVH * HDIM));
            int tl = tsub * 32 + j;
            float p0 = p_s[0][tl], p1 = p_s[1][tl], p2 = p_s[2][tl], p3 = p_s[3][tl];
            a0.x = fmaf(p0, vv.x, a0.x); a0.y = fmaf(p0, vv.y, a0.y); a0.z = fmaf(p0, vv.z, a0.z); a0.w = fmaf(p0, vv.w, a0.w);
            a1.x = fmaf(p1, vv.x, a1.x); a1.y = fmaf(p1, vv.y, a1.y); a1.z = fmaf(p1, vv.z, a1.z); a1.w = fmaf(p1, vv.w, a1.w);
            a2.x = fmaf(p2, vv.x, a2.x); a2.y = fmaf(p2, vv.y, a2.y); a2.z = fmaf(p2, vv.z, a2.z); a2.w = fmaf(p2, vv.w, a2.w);
            a3.x = fmaf(p3, vv.x, a3.x); a3.y = fmaf(p3, vv.y, a3.y); a3.z = fmaf(p3, vv.z, a3.z); a3.w = fmaf(p3, vv.w, a3.w);
        }
        if (split == ASPLIT - 1 && tsub == 7) { // pos POS from rv (cache unmutated)
            float4 vv = *(const float4*)(rv + (b * NKVH + kvh) * HDIM + q4 * 4);
            float p0 = p_s[0][255], p1 = p_s[1][255], p2 = p_s[2][255], p3 = p_s[3][255];
            a0.x = fmaf(p0, vv.x, a0.x); a0.y = fmaf(p0, vv.y, a0.y); a0.z = fmaf(p0, vv.z, a0.z); a0.w = fmaf(p0, vv.w, a0.w);
            a1.x = fmaf(p1, vv.x, a1.x); a1.y = fmaf(p1, vv.y, a1.y); a1.z = fmaf(p1, vv.z, a1.z); a1.w = fmaf(p1, vv.w, a1.w);
            a2.x = fmaf(p2, vv.x, a2.x); a2.y = fmaf(p2, vv.y, a2.y); a2.z = fmaf(p2, vv.z, a2.z); a2.w = fmaf(p2, vv.w, a2.w);
            a3.x = fmaf(p3, vv.x, a3.x); a3.y = fmaf(p3, vv.y, a3.y); a3.z = fmaf(p3, vv.z, a3.z); a3.w = fmaf(p3, vv.w, a3.w);
        }
        *(float4*)&red[tsub][0][q4 * 4] = a0;
        *(float4*)&red[tsub][1][q4 * 4] = a1;
        *(float4*)&red[tsub][2][q4 * 4] = a2;
        *(float4*)&red[tsub][3][q4 * 4] = a3;
    }
    __syncthreads();
    if (tid < 128) {
        int h = tid >> 5, qq = tid & 31;
        float4 s = {0, 0, 0, 0};
#pragma unroll
        for (int r = 0; r < 8; ++r) {
            float4 t4 = *(const float4*)&red[r][h][qq * 4];
            s.x += t4.x; s.y += t4.y; s.z += t4.z; s.w += t4.w;
        }
        int idx = ((b * NKVH + kvh) * ASPLIT + split) * 4 + h;
        *(float4*)(pacc + (size_t)idx * HDIM + qq * 4) = s;
    }
}

// combine split partials: grid 512 = (b, h), 128 threads; writes yT
__global__ void attn_combine_kernel(const float* __restrict__ pml,
                                    const float* __restrict__ pacc, float* __restrict__ yT) {
    int bid = blockIdx.x;
    int b = bid >> 4, h = bid & 15;
    int kvh = h >> 2, hl = h & 3;
    int d = threadIdx.x;
    float M = -INFINITY;
#pragma unroll
    for (int s = 0; s < ASPLIT; ++s) {
        int idx = ((b * NKVH + kvh) * ASPLIT + s) * 4 + hl;
        M = fmaxf(M, pml[2 * idx]);
    }
    float denom = 0.f, acc = 0.f;
#pragma unroll
    for (int s = 0; s < ASPLIT; ++s) {
        int idx = ((b * NKVH + kvh) * ASPLIT + s) * 4 + hl;
        float e = __expf(pml[2 * idx] - M);
        denom += pml[2 * idx + 1] * e;
        acc += e * pacc[(size_t)idx * HDIM + d];
    }
    yT[(size_t)(h * HDIM + d) * 32 + b] = acc / denom;
}

__global__ void silu_mul_kernel(float* __restrict__ g1, const float* __restrict__ g2) {
    int i = blockIdx.x * 256 + threadIdx.x; // 262144
    float a = g1[i], bb = g2[i];
    g1[i] = a * bb / (1.f + __expf(-a));
}

extern "C" void kernel_launch(void* const* d_in, const int* in_sizes, int n_in,
                              void* d_out, int out_size, void* d_ws, size_t ws_size,
                              hipStream_t stream) {
    (void)in_sizes; (void)n_in; (void)out_size; (void)ws_size;
    const float* x    = (const float*)d_in[0];
    const float* cosb = (const float*)d_in[1];
    const float* sinb = (const float*)d_in[2];
    const float* kc   = (const float*)d_in[3];
    const float* vc   = (const float*)d_in[4];
    const float* wra  = (const float*)d_in[5];
    const float* wq   = (const float*)d_in[6];
    const float* wk   = (const float*)d_in[7];
    const float* wv   = (const float*)d_in[8];
    const float* wo   = (const float*)d_in[9];
    const float* wrf  = (const float*)d_in[10];
    const float* w1   = (const float*)d_in[11];
    const float* w2   = (const float*)d_in[12];
    const float* w3   = (const float*)d_in[13];
    float* out = (float*)d_out;
    float* ws  = (float*)d_ws;

    float* qT   = ws + OFF_QT;
    float* kT   = ws + OFF_KT;
    float* vT   = ws + OFF_VT;
    float* g1T  = ws + OFF_G1;
    float* g2T  = ws + OFF_G2;
    float* xaT  = ws + OFF_XAT;
    float* rk   = ws + OFF_RK;
    float* rv   = ws + OFF_RV;
    float* pml  = ws + OFF_PML;
    float* pacc = ws + OFF_PACC;
    float* yT   = ws + OFF_YT;
    float* h    = ws + OFF_H;
    float* xfT  = ws + OFF_XFT;

    // zero all atomic-accumulated buffers (qT,kT,vT,g1T,g2T contiguous)
    zero_kernel<<<ZERO_N / 256, 256, 0, stream>>>(ws);

    // xaT = rmsnorm(x)^T, h = x
    rmsnorm_kernel<<<32, 256, 0, stream>>>(x, wra, xaT, h);
    // q,k,v (transposed outputs)
    gemv32_kernel<2048, 32, true><<<dim3(8, 64), 256, 0, stream>>>(xaT, wq, qT);
    gemv32_dual_kernel<512, 32, 2><<<dim3(4, 64), 256, 0, stream>>>(xaT, wk, wv, kT, vT);
    // rope new k,v (cache NOT mutated)
    rope_kernel<<<32, 256, 0, stream>>>(kT, vT, cosb, sinb, rk, rv);
    // attention
    attn_partial_kernel<<<2048, 256, 0, stream>>>(qT, kc, vc, rk, rv, pml, pacc);
    attn_combine_kernel<<<512, 128, 0, stream>>>(pml, pacc, yT);
    // h = x + y @ wo
    gemv32_kernel<2048, 32, false><<<dim3(8, 64), 256, 0, stream>>>(yT, wo, h);
    // xfT = rmsnorm(h)^T, out = h
    rmsnorm_kernel<<<32, 256, 0, stream>>>(h, wrf, xfT, out);
    // g1 = xf@w1, g2 = xf@w2 (transposed outputs)
    gemv32_dual_kernel<8192, 128, 32><<<dim3(64, 16), 256, 0, stream>>>(xfT, w1, w2, g1T, g2T);
    // g1 = silu(g1)*g2 (elementwise, layout-agnostic)
    silu_mul_kernel<<<1024, 256, 0, stream>>>(g1T, g2T);
    // out += g1 @ w3
    gemv32_kernel<2048, 128, false><<<dim3(8, 64), 256, 0, stream>>>(g1T, w3, out);
}